// Round 12
// baseline (58.653 us; speedup 1.0000x reference)
//
#include <hip/hip_runtime.h>
#include <hip/hip_bf16.h>
#include <stdint.h>

#define H 512
#define W 512
#define HW (H * W)
#define NSTRIP 128        // 4-row strips per image (k_mm granularity)

__device__ __forceinline__ int refl(int i, int n) {
    // BORDER_REFLECT_101: -1 -> 1, n -> n-2
    return i < 0 ? -i : (i >= n ? 2 * n - 2 - i : i);
}

// pack 8 gray bytes (trunc quantize) from 6 float4s into uint2
__device__ __forceinline__ uint2 gray8(float4 ra, float4 rb, float4 ga, float4 gb,
                                       float4 ba, float4 bb) {
    uint32_t t0 = (uint32_t)((0.2989f * ra.x + 0.587f * ga.x + 0.114f * ba.x) * 255.0f);
    uint32_t t1 = (uint32_t)((0.2989f * ra.y + 0.587f * ga.y + 0.114f * ba.y) * 255.0f);
    uint32_t t2 = (uint32_t)((0.2989f * ra.z + 0.587f * ga.z + 0.114f * ba.z) * 255.0f);
    uint32_t t3 = (uint32_t)((0.2989f * ra.w + 0.587f * ga.w + 0.114f * ba.w) * 255.0f);
    uint32_t t4 = (uint32_t)((0.2989f * rb.x + 0.587f * gb.x + 0.114f * bb.x) * 255.0f);
    uint32_t t5 = (uint32_t)((0.2989f * rb.y + 0.587f * gb.y + 0.114f * bb.y) * 255.0f);
    uint32_t t6 = (uint32_t)((0.2989f * rb.z + 0.587f * gb.z + 0.114f * bb.z) * 255.0f);
    uint32_t t7 = (uint32_t)((0.2989f * rb.w + 0.587f * gb.w + 0.114f * bb.w) * 255.0f);
    uint2 o;
    o.x = t0 | (t1 << 8) | (t2 << 16) | (t3 << 24);
    o.y = t4 | (t5 << 8) | (t6 << 16) | (t7 << 24);
    return o;
}

// ---------------- K1: pure gray stream (NO stencil, NO halo, NO dependencies) --------
// wave = 2 full rows of one source; 12 independent float4 loads -> 2 uint2 stores.
__global__ __launch_bounds__(256) void k_gray(const float* __restrict__ vis,
                                              const float* __restrict__ ir,
                                              uint8_t* __restrict__ qvis,
                                              uint8_t* __restrict__ qir, int B) {
    int lane = threadIdx.x & 63;
    int gwave = blockIdx.x * 4 + (threadIdx.x >> 6);   // [0, 2*B*256)
    int per_src = B * 256;               // 256 row-pairs per image
    int src = gwave >= per_src;
    int rem = src ? gwave - per_src : gwave;
    int b  = rem >> 8;
    int y0 = (rem & 255) * 2;

    const float4* p4 = (const float4*)((src ? ir : vis) + (size_t)b * 3 * HW);
    uint8_t* q = (src ? qir : qvis) + (size_t)b * HW;

    int o0 = y0 * (W / 4) + lane * 2;
    int o1 = o0 + (W / 4);
    float4 r0a = p4[o0],                 r0b = p4[o0 + 1];
    float4 g0a = p4[o0 + HW / 4],        g0b = p4[o0 + 1 + HW / 4];
    float4 b0a = p4[o0 + 2 * (HW / 4)],  b0b = p4[o0 + 1 + 2 * (HW / 4)];
    float4 r1a = p4[o1],                 r1b = p4[o1 + 1];
    float4 g1a = p4[o1 + HW / 4],        g1b = p4[o1 + 1 + HW / 4];
    float4 b1a = p4[o1 + 2 * (HW / 4)],  b1b = p4[o1 + 1 + 2 * (HW / 4)];

    uint2 q0 = gray8(r0a, r0b, g0a, g0b, b0a, b0b);
    uint2 q1 = gray8(r1a, r1b, g1a, g1b, b1a, b1b);
    *(uint2*)(q + (size_t)y0 * W + lane * 8)       = q0;
    *(uint2*)(q + (size_t)(y0 + 1) * W + lane * 8) = q1;
}

// Extract this lane's 10 stencil columns from an 8-byte row segment via shuffles.
__device__ __forceinline__ void row_cols(uint2 v, int lane, float* __restrict__ c) {
    uint32_t lx = __shfl_up(v.y, 1);
    uint32_t rx = __shfl_down(v.x, 1);
    uint32_t lb = (lane == 0)  ? ((v.x >> 8) & 0xffu)  : (lx >> 24);
    uint32_t rb = (lane == 63) ? ((v.y >> 16) & 0xffu) : (rx & 0xffu);
    c[0] = (float)lb;
    c[1] = (float)(v.x & 0xffu);
    c[2] = (float)((v.x >> 8) & 0xffu);
    c[3] = (float)((v.x >> 16) & 0xffu);
    c[4] = (float)(v.x >> 24);
    c[5] = (float)(v.y & 0xffu);
    c[6] = (float)((v.y >> 8) & 0xffu);
    c[7] = (float)((v.y >> 16) & 0xffu);
    c[8] = (float)(v.y >> 24);
    c[9] = (float)rb;
}

__device__ __forceinline__ void sobel_row8(const uint8_t* __restrict__ q, int y, int lane,
                                           float* __restrict__ mag) {
    const uint2* rm = (const uint2*)(q + (size_t)refl(y - 1, H) * W);
    const uint2* r0 = (const uint2*)(q + (size_t)y * W);
    const uint2* rp = (const uint2*)(q + (size_t)refl(y + 1, H) * W);
    uint2 vm = rm[lane], v0 = r0[lane], vp = rp[lane];
    float c0[10], c1[10], c2[10];
    row_cols(vm, lane, c0);
    row_cols(v0, lane, c1);
    row_cols(vp, lane, c2);
    float sx[10], sy[10];
    #pragma unroll
    for (int j = 0; j < 10; ++j) {
        sx[j] = c0[j] + 2.0f * c1[j] + c2[j];
        sy[j] = c2[j] - c0[j];
    }
    #pragma unroll
    for (int k = 0; k < 8; ++k) {
        float gx = sx[k + 2] - sx[k];
        float gy = sy[k] + 2.0f * sy[k + 1] + sy[k + 2];
        mag[k] = sqrtf(gx * gx + gy * gy);
    }
}

// ---------------- K2: sobel min/max from q (k_loss-shaped, uint2 loads) -------------
// wave = 4-row strip of one source; per-strip (mn,mx) -> pm via plain store.
__global__ __launch_bounds__(256) void k_mm(const uint8_t* __restrict__ qvis,
                                            const uint8_t* __restrict__ qir,
                                            float* __restrict__ pm, int B) {
    int lane = threadIdx.x & 63;
    int gwave = blockIdx.x * 4 + (threadIdx.x >> 6);   // [0, 2*B*NSTRIP)
    int per_src = B * NSTRIP;            // 2048
    int src = gwave >= per_src;
    int rem = src ? gwave - per_src : gwave;
    int b     = rem >> 7;
    int strip = rem & 127;
    int y0 = strip * 4;
    const uint8_t* q = (src ? qir : qvis) + (size_t)b * HW;

    float mn = INFINITY, mx = 0.0f;
    #pragma unroll
    for (int r = 0; r < 4; ++r) {
        float mag[8];
        sobel_row8(q, y0 + r, lane, mag);
        #pragma unroll
        for (int k = 0; k < 8; ++k) {
            mn = fminf(mn, mag[k]);
            mx = fmaxf(mx, mag[k]);
        }
    }
    #pragma unroll
    for (int o = 32; o > 0; o >>= 1) {
        mn = fminf(mn, __shfl_down(mn, o));
        mx = fmaxf(mx, __shfl_down(mx, o));
    }
    if (lane == 0) {
        float* o = pm + ((size_t)(src * B + b) * NSTRIP + strip) * 2;
        o[0] = mn;
        o[1] = mx;
    }
}

// ---------------- K3: minmax finalize + weighted blend + |diff| partial sums --------
__global__ __launch_bounds__(256) void k_loss(const float* __restrict__ vis,
                                              const float* __restrict__ ir,
                                              const float* __restrict__ fus,
                                              const uint8_t* __restrict__ qvis,
                                              const uint8_t* __restrict__ qir,
                                              const float* __restrict__ pm,
                                              float* __restrict__ partial, int B) {
    int w = threadIdx.x >> 6, lane = threadIdx.x & 63;
    int b = blockIdx.x >> 6;
    int y0 = (blockIdx.x & 63) * 8;

    __shared__ float sred[4];
    {
        int src = w >> 1, qsel = w & 1;
        const float* base = pm + (size_t)(src * B + b) * NSTRIP * 2;
        float v0 = base[lane * 2 + qsel];
        float v1 = base[(lane + 64) * 2 + qsel];
        float v = qsel ? fmaxf(v0, v1) : fminf(v0, v1);
        if (qsel == 0) {
            #pragma unroll
            for (int o = 32; o > 0; o >>= 1) v = fminf(v, __shfl_down(v, o));
        } else {
            #pragma unroll
            for (int o = 32; o > 0; o >>= 1) v = fmaxf(v, __shfl_down(v, o));
        }
        if (lane == 0) sred[w] = v;
    }
    __syncthreads();
    float mn_v = sred[0], mx_v = sred[1], mn_i = sred[2], mx_i = sred[3];
    float inv_v = 1.0f / fmaxf(mx_v - mn_v, 1e-8f);
    float inv_i = 1.0f / fmaxf(mx_i - mn_i, 1e-8f);

    float acc = 0.0f;
    #pragma unroll
    for (int rr = 0; rr < 2; ++rr) {
        int y = y0 + w + rr * 4;
        float mv[8], mi[8];
        sobel_row8(qvis + (size_t)b * HW, y, lane, mv);
        sobel_row8(qir  + (size_t)b * HW, y, lane, mi);

        float wv[8], wi[8];
        #pragma unroll
        for (int k = 0; k < 8; ++k) {
            float sv = (mv[k] - mn_v) * inv_v;
            float si = (mi[k] - mn_i) * inv_i;
            float den = sv + si + 1e-8f;
            float rden = 1.0f / den;
            wv[k] = sv * rden;
            wi[k] = si * rden;
        }

        int i = y * W + lane * 8;
        #pragma unroll
        for (int ch = 0; ch < 3; ++ch) {
            size_t e4 = ((((size_t)b * 3 + ch) * HW) + i) >> 2;
            const float4* v4 = (const float4*)vis;
            const float4* r4 = (const float4*)ir;
            const float4* f4 = (const float4*)fus;
            float4 va = v4[e4], vb = v4[e4 + 1];
            float4 ra = r4[e4], rb = r4[e4 + 1];
            float4 fa = f4[e4], fb = f4[e4 + 1];
            acc += fabsf(wv[0] * va.x + wi[0] * ra.x - fa.x);
            acc += fabsf(wv[1] * va.y + wi[1] * ra.y - fa.y);
            acc += fabsf(wv[2] * va.z + wi[2] * ra.z - fa.z);
            acc += fabsf(wv[3] * va.w + wi[3] * ra.w - fa.w);
            acc += fabsf(wv[4] * vb.x + wi[4] * rb.x - fb.x);
            acc += fabsf(wv[5] * vb.y + wi[5] * rb.y - fb.y);
            acc += fabsf(wv[6] * vb.z + wi[6] * rb.z - fb.z);
            acc += fabsf(wv[7] * vb.w + wi[7] * rb.w - fb.w);
        }
    }

    #pragma unroll
    for (int o = 32; o > 0; o >>= 1) acc += __shfl_down(acc, o);
    __shared__ float ssum[4];
    if (lane == 0) ssum[w] = acc;
    __syncthreads();
    if (threadIdx.x == 0) partial[blockIdx.x] = ssum[0] + ssum[1] + ssum[2] + ssum[3];
}

// ---------------- K4: final reduce ----------------
__global__ void k_final(const float* __restrict__ partial, int n, float* __restrict__ out,
                        long long N) {
    double s = 0.0;
    for (int i = threadIdx.x; i < n; i += 256) s += (double)partial[i];
    __shared__ double sm[256];
    sm[threadIdx.x] = s;
    __syncthreads();
    for (int k = 128; k > 0; k >>= 1) {
        if (threadIdx.x < k) sm[threadIdx.x] += sm[threadIdx.x + k];
        __syncthreads();
    }
    if (threadIdx.x == 0) out[0] = (float)(sm[0] / (double)N);
}

extern "C" void kernel_launch(void* const* d_in, const int* in_sizes, int n_in,
                              void* d_out, int out_size, void* d_ws, size_t ws_size,
                              hipStream_t stream) {
    const float* vis = (const float*)d_in[0];
    const float* ir  = (const float*)d_in[1];
    const float* fus = (const float*)d_in[2];
    int B = in_sizes[0] / (3 * HW);  // 16

    uint8_t* qvis = (uint8_t*)d_ws;
    uint8_t* qir  = qvis + (size_t)B * HW;
    float* pm      = (float*)(qir + (size_t)B * HW);       // 2*B*128*2 floats
    float* partial = pm + (size_t)2 * B * NSTRIP * 2;      // 1024 floats
    float* out = (float*)d_out;

    int nblk_gray = 2 * B * 256 / 4;    // 2048 blocks x 4 waves = 8192 waves
    k_gray<<<nblk_gray, 256, 0, stream>>>(vis, ir, qvis, qir, B);

    int nblk_mm = 2 * B * NSTRIP / 4;   // 1024 blocks x 4 waves = 4096 waves
    k_mm<<<nblk_mm, 256, 0, stream>>>(qvis, qir, pm, B);

    int nblk_loss = B * (H / 8);        // 1024 blocks
    k_loss<<<nblk_loss, 256, 0, stream>>>(vis, ir, fus, qvis, qir, pm, partial, B);

    k_final<<<1, 256, 0, stream>>>(partial, nblk_loss, out, (long long)B * 3 * HW);
}